// Round 6
// baseline (597.377 us; speedup 1.0000x reference)
//
#include <hip/hip_runtime.h>

// Linear-chain CRF log-partition (backward DP), B=64, S=1024, T=128.
//
// r17 = r16's zero-global inner loop (373us rocprof, proven) restructured
// to a 2-wave / one-full-row-per-lane matvec + hoisted em-prefetch.
//
// r16 post-mortem: VGPR=88, staging works; remaining ~874 cyc/step is the
// exchange chain (write -> lgkm -> 4-wave barrier -> LDS RT -> dots ->
// 2-stage DPP) PLUS a fully-serialized en ds_read+exp at the loop bottom
// (~130 cyc naked on the chain).
//
// r17 changes:
//  1) 128 threads (2 waves); lane j owns row j of E (64 packed f16-pair
//     VGPRs, all 128 cols) -> complete row dot in-lane: NO DPP reduction,
//     2-wave barrier instead of 4-wave. (+32 dot2/lane: issue is cheap,
//     the chain is latency-bound.)
//  2) en read + exp hoisted inside the active block right after the
//     barrier -> latency hides under the vbuf-read + dot phase.
//  Why this won't repeat r15's flop (VGPR=52, in-loop global reloads):
//     (a) em from LDS staging (r16), no global in loop; (b) KEEP16 x4
//     per iteration forces all 64 E values simultaneously live — and at
//     ~110 total regs this FITS, so residency is the cheap option (r13's
//     failure was 128 E regs vs a 132 budget — didn't fit);
//     (c) __launch_bounds__(128,1) allows up to 512 regs.
//
// Gates: VGPR_Count ~105-132 (50-90 = allocator betrayal -> fall back to
// r16+hoist next round); dur ~190-250us rocprof.
//
// Numerics IDENTICAL to r11/r16 (passed, absmax 0.0): publish v' = q*us*
// e^{-GHAT} (f16, dead-beat); barrier; z = zslot[par]; q <- (E v')*rcp(z);
// Lam += GHAT + log z.

typedef _Float16 h2 __attribute__((ext_vector_type(2)));

#define B_  64
#define S_  1024
#define T_  128
#define PAD_IDX 0
#define EOS_IDX 3
#define BOT_IDX 1
#define GHAT         5.35f
#define EXP_NEG_GHAT 0.004736892f   // e^{-5.35}

#define CHUNK_BYTES  32768          // 64 steps * 128 rows * 4 B

#if defined(__has_builtin)
#if __has_builtin(__builtin_amdgcn_fdot2)
#define HAS_FDOT2 1
#endif
#endif

static __device__ __forceinline__ float dot2acc(unsigned eu, unsigned pu, float c) {
  h2 a = __builtin_bit_cast(h2, eu);
  h2 b = __builtin_bit_cast(h2, pu);
#ifdef HAS_FDOT2
  return __builtin_amdgcn_fdot2(a, b, c, false);
#else
  return fmaf((float)a.x, (float)b.x, fmaf((float)a.y, (float)b.y, c));
#endif
}

// Force 16 values simultaneously live in VGPRs at this point (0 instrs).
#define KEEP16(A, o) \
  asm volatile("" :: "v"(A[(o)+0]),  "v"(A[(o)+1]),  "v"(A[(o)+2]),  "v"(A[(o)+3]),  \
                     "v"(A[(o)+4]),  "v"(A[(o)+5]),  "v"(A[(o)+6]),  "v"(A[(o)+7]),  \
                     "v"(A[(o)+8]),  "v"(A[(o)+9]),  "v"(A[(o)+10]), "v"(A[(o)+11]), \
                     "v"(A[(o)+12]), "v"(A[(o)+13]), "v"(A[(o)+14]), "v"(A[(o)+15]))

typedef __attribute__((address_space(3))) void  lds_void_t;
typedef __attribute__((address_space(1))) const void gmem_void_t;

__global__ __launch_bounds__(128, 1)
void crf_logz_kernel(
    const int*   __restrict__ W,
    const float* __restrict__ emissions,
    const float* __restrict__ transitions,
    float*       __restrict__ out)
{
  const int b   = blockIdx.x;
  const int tid = threadIdx.x;       // 0..127 — two waves
  const int l   = tid & 63;
  const int j   = tid;               // owned row of E / beta

  __shared__ __align__(16) float          embuf[2][64 * T_];  // 2 x 32 KB em chunks
  __shared__ __align__(16) unsigned short vbuf[2][T_];        // [parity][row] f16 v'
  __shared__ float zslot[2];
  __shared__ float fbuf[T_];

  // ---- E row j (all 128 cols) as 64 packed f16 pairs -> 64 VGPRs
  unsigned Eu[64];
  {
    const float2* tr = (const float2*)(transitions + (size_t)j * T_);
    #pragma unroll
    for (int k = 0; k < 64; ++k) {
      float2 x = tr[k];
      h2 e; e.x = (_Float16)__expf(x.x); e.y = (_Float16)__expf(x.y);
      Eu[k] = __builtin_bit_cast(unsigned, e);
    }
  }

  if (tid == 0) { zslot[0] = 1.0f; zslot[1] = 1.0f; }

  const int*  Wrow = W + b * S_;
  const char* emB  = (const char*)(emissions + (size_t)b * S_ * T_);

  // async stage of one 32 KB chunk into embuf[nb]; 16 rounds x 2 KB.
  // per wave the LDS dest base is uniform; HW adds lane*16.
  auto stage_chunk = [&](int chunk, int nb) {
    const char* gbase = emB + (size_t)chunk * CHUNK_BYTES + (size_t)tid * 16;
    char* lbase = (char*)&embuf[nb][0] + ((tid >> 6) << 10);
    #pragma unroll
    for (int r = 0; r < 16; ++r) {
      __builtin_amdgcn_global_load_lds(
          (gmem_void_t*)(gbase + (r << 11)),
          (lds_void_t*)(lbase + (r << 11)),
          16, 0, 0);
    }
  };

  // prologue: stage chunk 15 -> buf 0; prefetch chunk 15's W ids
  stage_chunk(15, 0);
  int wtok = Wrow[(15 << 6) + l];
  __syncthreads();                    // full drain (vmcnt+lgkm) once
  unsigned long long m = __ballot((wtok != PAD_IDX) & (wtok != EOS_IDX));

  float q   = 1.0f;                   // exp-state for row j
  float Lam = 0.0f;
  int   par = 0;
  int   cur = 0;

  for (int c = 15; c >= 0; --c) {
    if (c > 0) {
      stage_chunk(c - 1, cur ^ 1);          // async; drains at boundary only
      wtok = Wrow[((c - 1) << 6) + l];      // W one chunk ahead (vmcnt)
    }
    // init us for within-chunk step 63 (staging of THIS buffer already drained)
    float us0;
    {
      float ec = embuf[cur][(63 << 7) + j];
      us0 = __expf(ec) * EXP_NEG_GHAT;
    }

    const int lo = (c == 0) ? 1 : 0;        // i==0 is never consumed

    for (int bit = 63; bit >= lo; --bit) {
      // keep all 64 E registers simultaneously live (zero instructions)
      KEEP16(Eu, 0);  KEEP16(Eu, 16);  KEEP16(Eu, 32);  KEEP16(Eu, 48);

      const bool active = (long long)m < 0; // top bit; uniform across block
      m <<= 1;
      int nb2 = bit - 1; nb2 &= ~(nb2 >> 31);   // max(bit-1,0); tail unused

      if (active) {                         // block-uniform branch
        // publish v' = q * us  (one f16 per lane = its row)
        _Float16 vh = (_Float16)(q * us0);
        vbuf[par][j] = __builtin_bit_cast(unsigned short, vh);
        // drain own DS write, then barrier; NO vmcnt drain (staging lives)
        asm volatile("s_waitcnt lgkmcnt(0)\n\ts_barrier" ::: "memory");

        // hoisted em prefetch: latency hides under vbuf reads + dots
        float enf = embuf[cur][(nb2 << 7) + j];
        float z   = zslot[par];

        const uint4* vb = (const uint4*)&vbuf[par][0];
        float a0=0.f,a1=0.f,a2=0.f,a3=0.f,a4=0.f,a5=0.f,a6=0.f,a7=0.f;
        #pragma unroll
        for (int k = 0; k < 16; ++k) {
          uint4 pv = vb[k];                 // broadcast b128: pairs 4k..4k+3
          if (k & 1) {
            a4 = dot2acc(Eu[4*k+0], pv.x, a4);
            a5 = dot2acc(Eu[4*k+1], pv.y, a5);
            a6 = dot2acc(Eu[4*k+2], pv.z, a6);
            a7 = dot2acc(Eu[4*k+3], pv.w, a7);
          } else {
            a0 = dot2acc(Eu[4*k+0], pv.x, a0);
            a1 = dot2acc(Eu[4*k+1], pv.y, a1);
            a2 = dot2acc(Eu[4*k+2], pv.z, a2);
            a3 = dot2acc(Eu[4*k+3], pv.w, a3);
          }
        }
        float s = ((a0 + a4) + (a1 + a5)) + ((a2 + a6) + (a3 + a7));

        float rz = __builtin_amdgcn_rcpf(z);  // uniform; off the dot chain
        q = s * rz;
        if (tid == 0) zslot[par ^ 1] = q;     // row 0's value for NEXT step
        Lam += GHAT + __logf(z);              // exact compensation (off-path)
        par ^= 1;
        us0 = __expf(enf) * EXP_NEG_GHAT;     // exp scheduled under dots
      } else {
        float enf = embuf[cur][(nb2 << 7) + j];
        us0 = __expf(enf) * EXP_NEG_GHAT;
      }
    }

    if (c > 0) {
      // chunk boundary: all staging loads (and next W) land; flip buffers
      asm volatile("s_waitcnt vmcnt(0)\n\ts_barrier" ::: "memory");
      m = __ballot((wtok != PAD_IDX) & (wtok != EOS_IDX));
      cur ^= 1;
    }
  }

  // ---- epilogue: f_j = trans[BOT,j] + em[b,0,j] + log q_j; out = Lam+LSE(f)
  // chunk 0 still lives in embuf[cur]; step 0 = em[b,0,*]
  float f = transitions[(size_t)BOT_IDX * T_ + j] + embuf[cur][j] + __logf(q);
  fbuf[j] = f;
  __syncthreads();
  if (tid < 64) {
    float x0 = fbuf[tid], x1 = fbuf[tid + 64];
    float m2 = fmaxf(x0, x1);
    #pragma unroll
    for (int off = 32; off; off >>= 1) m2 = fmaxf(m2, __shfl_xor(m2, off));
    float s = __expf(x0 - m2) + __expf(x1 - m2);
    #pragma unroll
    for (int off = 32; off; off >>= 1) s += __shfl_xor(s, off);
    if (tid == 0) out[b] = Lam + m2 + __logf(s);
  }
}

extern "C" void kernel_launch(void* const* d_in, const int* in_sizes, int n_in,
                              void* d_out, int out_size, void* d_ws, size_t ws_size,
                              hipStream_t stream) {
  const int*   W     = (const int*)d_in[0];
  const float* em    = (const float*)d_in[1];
  const float* trans = (const float*)d_in[2];
  float*       out   = (float*)d_out;
  (void)in_sizes; (void)n_in; (void)out_size; (void)d_ws; (void)ws_size;
  crf_logz_kernel<<<B_, 128, 0, stream>>>(W, em, trans, out);
}

// Round 8
// 342.526 us; speedup vs baseline: 1.7440x; 1.7440x over previous
//
#include <hip/hip_runtime.h>

// Linear-chain CRF log-partition, B=64, S=1024, T=128.
//
// r19 = r18 (associative matrix-product scan + MFMA) with the cvt_pkrtz
// return-type compile fix (__fp16 vec2 -> bit_cast to unsigned directly).
//
// r11-r17 verdict: the vector-recurrence architecture is latency-bound on
// a 1024-step serial chain with a measured ~875 cyc/step floor (r16) that
// resisted 6 rounds of chain-shortening; designs needing >32 E regs/lane
// hit a hard allocator wall (132) three separate ways. Pivot to a
// formulation whose bound is THROUGHPUT, not latency:
//
//   q_final = T_1 T_2 ... T_1023 q0,   T_i = (E*e^{-GHAT}) * diag(exp(em_i))
//
// Split into G=16 segments x L=64 steps. Kernel 1 (64x16 blocks, 256 thr):
// build each segment's 128x128 product with <=64 serial matmuls on MFMA
// 16x16x32 f16 (verified layouts: C col=lane&15,row=(lane>>4)*4+reg;
// A/B: 8 contiguous-K f16 per lane, lane&15 = row(A)/col(B), lane>>4
// selects the 8-K group). B-operand (current product, row-scaled by
// exp(em)) lives in double-buffered swizzled LDS (2x32KB); one barrier
// per step. Cost = LDS BW: 160KB/block-step -> 10.5 GB total -> ~152us
// floor at 69 TB/s. Kernel 2 (64 blocks): apply the 16 segment matrices
// to q0 serially, add GHAT * (#active steps), LSE epilogue.
//
// Numerics: e^{-GHAT} folded into E (A-side) keeps every f16 intermediate
// in normal range (E' ~ 4.7e-3, published B = exp(em_r)*M in [1e-4, 55],
// M steady ~8e-3). f16 chain depth ~80 vs the previously-passing 1023-deep
// f16 dot chain. f32 MFMA accum; f32 combine.
//
// Workspace: 64*16*128*128 f16 = 32 MB of d_ws.

typedef _Float16 h8 __attribute__((ext_vector_type(8)));
typedef float    f4 __attribute__((ext_vector_type(4)));

#define B_  64
#define S_  1024
#define T_  128
#define G_  16
#define PAD_IDX 0
#define EOS_IDX 3
#define BOT_IDX 1
#define GHAT         5.35f
#define EXP_NEG_GHAT 0.004736892f   // e^{-5.35}

// swizzled LDS byte offset for B-operand element (n = col, k = row-of-M).
// slot XOR spreads the 16B slots so frag reads/writes hit all banks evenly.
__device__ __forceinline__ int baddr16(int n, int k_slot /*k>>3*/) {
  return n * 256 + (((k_slot ^ n) & 15) << 4);
}

// ---------------- kernel 1: per-segment matrix product ----------------
__global__ __launch_bounds__(256)
void crf_seg_kernel(const int* __restrict__ W,
                    const float* __restrict__ emissions,
                    const float* __restrict__ transitions,
                    _Float16* __restrict__ ws)
{
  const int b = blockIdx.x, g = blockIdx.y;
  const int tid  = threadIdx.x;
  const int w    = tid >> 6;        // wave 0..3 -> output rows [32w, 32w+32)
  const int lane = tid & 63;
  const int lr   = lane & 15;       // row-in-tile (A) / col-in-tile (B,C)
  const int lg   = lane >> 4;       // 8-wide K group (A,B) / 4-row group (C)

  __shared__ __align__(16) char bbuf[2][32768];   // double-buffered B operand

  // --- segment activity mask (identical in all 4 waves)
  int tok = W[b * S_ + g * 64 + lane];
  unsigned long long mask = __ballot((tok != PAD_IDX) & (tok != EOS_IDX));
  if (g == 0) mask &= ~1ull;                      // i==0 never consumed

  const size_t segoff = ((size_t)(b * G_ + g)) << 14;   // 16384 f16 per segment

  if (mask == 0ull) {                             // empty segment: S_g = I
    int r = tid >> 1, c0 = (tid & 1) << 6;
    #pragma unroll
    for (int e8 = 0; e8 < 8; ++e8) {
      h8 v;
      #pragma unroll
      for (int e = 0; e < 8; ++e)
        v[e] = (r == c0 + e8 * 8 + e) ? (_Float16)1.f : (_Float16)0.f;
      *(h8*)(ws + segoff + (size_t)r * T_ + c0 + e8 * 8) = v;
    }
    return;
  }

  // --- A operand: E' = exp(transitions) * e^{-GHAT}, rows [32w,32w+32)
  // frag EA[rtl][kb]: A[row = 32w+16rtl+lr][k = kb*32 + lg*8 + j]
  h8 EA[2][4];
  #pragma unroll
  for (int rtl = 0; rtl < 2; ++rtl) {
    const int row = 32 * w + 16 * rtl + lr;
    #pragma unroll
    for (int kb = 0; kb < 4; ++kb) {
      const float4* tp = (const float4*)(transitions + (size_t)row * T_ + kb * 32 + lg * 8);
      float4 v0 = tp[0], v1 = tp[1];
      h8 f;
      f[0] = (_Float16)(__expf(v0.x) * EXP_NEG_GHAT);
      f[1] = (_Float16)(__expf(v0.y) * EXP_NEG_GHAT);
      f[2] = (_Float16)(__expf(v0.z) * EXP_NEG_GHAT);
      f[3] = (_Float16)(__expf(v0.w) * EXP_NEG_GHAT);
      f[4] = (_Float16)(__expf(v1.x) * EXP_NEG_GHAT);
      f[5] = (_Float16)(__expf(v1.y) * EXP_NEG_GHAT);
      f[6] = (_Float16)(__expf(v1.z) * EXP_NEG_GHAT);
      f[7] = (_Float16)(__expf(v1.w) * EXP_NEG_GHAT);
      EA[rtl][kb] = f;
    }
  }

  // --- init: Bbuf[0] = diag(exp(em[i_hi]))  (first matmul applies T_hi)
  const int hib = 63 - __builtin_clzll(mask);
  {
    char* bz = &bbuf[0][0] + tid * 128;           // zero 32 KB cooperatively
    #pragma unroll
    for (int r = 0; r < 8; ++r) *(uint4*)(bz + r * 16) = uint4{0u, 0u, 0u, 0u};
  }
  __syncthreads();
  if (tid < T_) {
    float e = emissions[((size_t)b * S_ + (g * 64 + hib)) * T_ + tid];
    *(_Float16*)(&bbuf[0][baddr16(tid, tid >> 3) + (tid & 7) * 2]) = (_Float16)__expf(e);
  }

  // --- next-active scan + em prefetch (one step ahead)
  unsigned long long rem = mask & ~(1ull << hib);
  int inb = rem ? (63 - __builtin_clzll(rem)) : -1;
  const int base_r = 32 * w + lg * 4;             // first C row of this lane
  float4 elo, ehi;
  {
    int idx = (inb < 0) ? 0 : (g * 64 + inb);
    const float* ep = emissions + ((size_t)b * S_ + idx) * T_;
    elo = *(const float4*)(ep + base_r);
    ehi = *(const float4*)(ep + base_r + 16);
  }

  int p = 0;
  f4 acc[2][8];
  for (;;) {
    __syncthreads();                              // Bbuf[p] ready for all waves

    #pragma unroll
    for (int rtl = 0; rtl < 2; ++rtl)
      #pragma unroll
      for (int ct = 0; ct < 8; ++ct) acc[rtl][ct] = f4{0.f, 0.f, 0.f, 0.f};

    #pragma unroll
    for (int kb = 0; kb < 4; ++kb) {
      #pragma unroll
      for (int ct = 0; ct < 8; ++ct) {
        const int n = ct * 16 + lr;
        h8 bf = *(const h8*)(&bbuf[p][baddr16(n, kb * 4 + lg)]);
        acc[0][ct] = __builtin_amdgcn_mfma_f32_16x16x32_f16(EA[0][kb], bf, acc[0][ct], 0, 0, 0);
        acc[1][ct] = __builtin_amdgcn_mfma_f32_16x16x32_f16(EA[1][kb], bf, acc[1][ct], 0, 0, 0);
      }
    }

    if (inb < 0) break;                           // uniform: acc = S_g, done

    // us = exp(em[i_next]) for this lane's 8 C rows (prefetched last iter)
    f4 ulo, uhi;
    ulo[0] = __expf(elo.x); ulo[1] = __expf(elo.y);
    ulo[2] = __expf(elo.z); ulo[3] = __expf(elo.w);
    uhi[0] = __expf(ehi.x); uhi[1] = __expf(ehi.y);
    uhi[2] = __expf(ehi.z); uhi[3] = __expf(ehi.w);

    rem &= ~(1ull << inb);
    int inn = rem ? (63 - __builtin_clzll(rem)) : -1;
    {
      int idx = (inn < 0) ? 0 : (g * 64 + inn);   // clamp: value unused if -1
      const float* ep = emissions + ((size_t)b * S_ + idx) * T_;
      elo = *(const float4*)(ep + base_r);
      ehi = *(const float4*)(ep + base_r + 16);
    }

    // publish Bbuf[p^1] = diag(us) * acc  (f16, swizzled)
    #pragma unroll
    for (int rtl = 0; rtl < 2; ++rtl) {
      const int k0 = 32 * w + 16 * rtl + lg * 4;  // first row; 4 consecutive
      const int ks = k0 >> 3;
      const int sub = (k0 & 7) * 2;               // 0 or 8 within the 16B slot
      const f4 u = rtl ? uhi : ulo;
      #pragma unroll
      for (int ct = 0; ct < 8; ++ct) {
        const int n = ct * 16 + lr;
        f4 c = acc[rtl][ct];
        uint2 d;
        d.x = __builtin_bit_cast(unsigned,
                __builtin_amdgcn_cvt_pkrtz(c[0] * u[0], c[1] * u[1]));
        d.y = __builtin_bit_cast(unsigned,
                __builtin_amdgcn_cvt_pkrtz(c[2] * u[2], c[3] * u[3]));
        *(uint2*)(&bbuf[p ^ 1][baddr16(n, ks) + sub]) = d;
      }
    }
    p ^= 1;
    inb = inn;
  }

  // --- store S_g (unscaled accumulators) to workspace, row-major f16
  #pragma unroll
  for (int rtl = 0; rtl < 2; ++rtl) {
    const int k0 = 32 * w + 16 * rtl + lg * 4;
    #pragma unroll
    for (int ct = 0; ct < 8; ++ct) {
      const int n = ct * 16 + lr;
      #pragma unroll
      for (int r = 0; r < 4; ++r)
        ws[segoff + (size_t)(k0 + r) * T_ + n] = (_Float16)acc[rtl][ct][r];
    }
  }
}

// ---------------- kernel 2: combine segments + epilogue ----------------
__global__ __launch_bounds__(128)
void crf_combine_kernel(const int* __restrict__ W,
                        const float* __restrict__ emissions,
                        const float* __restrict__ transitions,
                        const _Float16* __restrict__ ws,
                        float* __restrict__ out)
{
  const int b = blockIdx.x, t = threadIdx.x;
  __shared__ float qv[T_];
  __shared__ float redf[128];
  __shared__ int   redi[128];

  qv[t] = 1.0f;
  __syncthreads();

  // apply S_15 first, S_0 last:  q = S_0 S_1 ... S_15 * 1
  for (int g = G_ - 1; g >= 0; --g) {
    const _Float16* Sg = ws + (((size_t)(b * G_ + g)) << 14) + (size_t)t * T_;
    float acc = 0.f;
    #pragma unroll
    for (int j8 = 0; j8 < 16; ++j8) {
      h8 v = *(const h8*)(Sg + j8 * 8);
      float4 q0 = *(const float4*)&qv[j8 * 8];
      float4 q1 = *(const float4*)&qv[j8 * 8 + 4];
      acc += (float)v[0] * q0.x + (float)v[1] * q0.y
           + (float)v[2] * q0.z + (float)v[3] * q0.w
           + (float)v[4] * q1.x + (float)v[5] * q1.y
           + (float)v[6] * q1.z + (float)v[7] * q1.w;
    }
    __syncthreads();
    qv[t] = acc;
    __syncthreads();
  }

  // k = number of active steps (i in [1,1023]) for the GHAT compensation
  int cnt = 0;
  #pragma unroll
  for (int c = 0; c < 8; ++c) {
    int i = c * 128 + t;
    if (i >= 1) {
      int tk = W[b * S_ + i];
      cnt += ((tk != PAD_IDX) & (tk != EOS_IDX)) ? 1 : 0;
    }
  }

  float term = __expf(transitions[BOT_IDX * T_ + t]
                      + emissions[(size_t)b * S_ * T_ + t]) * qv[t];
  redf[t] = term;
  redi[t] = cnt;
  __syncthreads();
  #pragma unroll
  for (int off = 64; off > 0; off >>= 1) {
    if (t < off) { redf[t] += redf[t + off]; redi[t] += redi[t + off]; }
    __syncthreads();
  }
  if (t == 0) out[b] = GHAT * (float)redi[0] + logf(redf[0]);
}

extern "C" void kernel_launch(void* const* d_in, const int* in_sizes, int n_in,
                              void* d_out, int out_size, void* d_ws, size_t ws_size,
                              hipStream_t stream) {
  const int*   W     = (const int*)d_in[0];
  const float* em    = (const float*)d_in[1];
  const float* trans = (const float*)d_in[2];
  float*       out   = (float*)d_out;
  _Float16*    wsp   = (_Float16*)d_ws;          // needs 32 MB
  (void)in_sizes; (void)n_in; (void)out_size; (void)ws_size;

  crf_seg_kernel<<<dim3(B_, G_), 256, 0, stream>>>(W, em, trans, wsp);
  crf_combine_kernel<<<B_, 128, 0, stream>>>(W, em, trans, wsp, out);
}